// Round 14
// baseline (215.530 us; speedup 1.0000x reference)
//
#include <hip/hip_runtime.h>
#include <math.h>

#define D_DIM 4096
#define NWG 1536  // 6 WGs/CU x 256 CUs, persistent grid-stride (~10.7 rows/WG)

typedef float v2f __attribute__((ext_vector_type(2)));

// ---- packed-f32 butterfly primitives (VOP3P) ----
__device__ __forceinline__ v2f bfly0(v2f a) {
    v2f d;
    asm("v_pk_add_f32 %0, %1, %2 op_sel:[0,1] op_sel_hi:[0,1] neg_hi:[0,1]"
        : "=v"(d) : "v"(a), "v"(a));
    return d;
}
__device__ __forceinline__ v2f pkadd(v2f a, v2f b) {
    v2f d; asm("v_pk_add_f32 %0, %1, %2" : "=v"(d) : "v"(a), "v"(b)); return d;
}
__device__ __forceinline__ v2f pksub(v2f a, v2f b) {
    v2f d; asm("v_pk_add_f32 %0, %1, %2 neg_lo:[0,1] neg_hi:[0,1]" : "=v"(d) : "v"(a), "v"(b)); return d;
}
__device__ __forceinline__ v2f pkmul(v2f a, v2f b) {
    v2f d; asm("v_pk_mul_f32 %0, %1, %2" : "=v"(d) : "v"(a), "v"(b)); return d;
}

// In-register FWHT over 4 bits: 16 values as 8 packed v2f (verified r2-r11).
__device__ __forceinline__ void radix16(v2f w[8]) {
#pragma unroll
    for (int p = 0; p < 8; ++p) w[p] = bfly0(w[p]);
#pragma unroll
    for (int s = 0; s < 3; ++s) {
        const int d = 1 << s;
#pragma unroll
        for (int p = 0; p < 8; ++p) {
            if (!(p & d)) {
                const v2f a = w[p];
                const v2f b = w[p + d];
                w[p]     = pkadd(a, b);
                w[p + d] = pksub(a, b);
            }
        }
    }
}

// Phase barrier: drain DS ops only (stores/loads in flight stay in flight;
// __syncthreads would add a vmcnt(0) drain). Verified in R11.
__device__ __forceinline__ void phase_barrier() {
    asm volatile("s_waitcnt lgkmcnt(0)" ::: "memory");
    __builtin_amdgcn_s_barrier();
    __builtin_amdgcn_sched_barrier(0);
}

// Rank-complete transpose-buffer swizzle (verified R11: conflict-free):
//   b4 ^= e8 ^ e5 ;  b3 ^= e7 ;  b2 ^= e9 ^ e6
// Phases A/E (stride-256) and B/D (stride-16): 2-way banks (free);
// phase C b128: at the bank floor. Bijective involution; bits 1:0 untouched.
__device__ __forceinline__ int swzW(int e) {
    const int x4 = ((e >> 8) ^ (e >> 5)) & 1;
    const int x3 = (e >> 7) & 1;
    const int x2 = ((e >> 9) ^ (e >> 6)) & 1;
    return e ^ (x4 << 4) ^ (x3 << 3) ^ (x2 << 2);
}

// u in NATURAL order, 1/64 FWHT normalization folded in.
__global__ void compute_u_kernel(const float* __restrict__ g_mu,
                                 const float* __restrict__ g_rho,
                                 const float* __restrict__ eps,
                                 float* __restrict__ u) {
    const int i = blockIdx.x * blockDim.x + threadIdx.x;
    if (i < D_DIM) {
        const float r = g_rho[i];
        const float sp = (r > 20.0f) ? r : log1pf(expf(r));
        u[i] = (g_mu[i] + sp * eps[i]) * 0.015625f;
    }
}

// Persistent cooperative kernel, occupancy-first variant of R11:
//  - NO stage buffer / glds / manual vmcnt: x loaded straight to registers
//    (16 coalesced b32 per thread), latency hidden by 24 waves/CU TLP.
//  - single 16 KB trb per WG -> 6 WG/CU (launch_bounds cap), 24 waves/CU.
//  - NO persistent scale registers (R10's spill cause): S1/S2/U reloaded
//    per row from L2 as short-lived transients.
//  - 5-phase dataflow + swzW verbatim from R11 (verified).
__global__ __launch_bounds__(256, 6) void whvi_kernel(const float* __restrict__ x,
                                                      const float* __restrict__ s1,
                                                      const float* __restrict__ s2,
                                                      const float* __restrict__ u,
                                                      float* __restrict__ out,
                                                      int nrows) {
    __shared__ float trb[D_DIM];  // 16 KB transpose buffer, swzW layout
    const int tid = threadIdx.x;

    for (int row = blockIdx.x; row < nrows; row += NWG) {
        const float* __restrict__ xr = x + (size_t)row * D_DIM;
        v2f w[8];

        // ---- Phase A: x*s2 from global (coalesced b32), FWHT bits 8-11 ----
#pragma unroll
        for (int m = 0; m < 16; ++m) {
            const int i = tid + (m << 8);
            const float val = xr[i] * s2[i];
            if (m & 1) w[m >> 1].y = val; else w[m >> 1].x = val;
        }
        radix16(w);
#pragma unroll
        for (int m = 0; m < 16; ++m)
            trb[swzW(tid + (m << 8))] = (m & 1) ? w[m >> 1].y : w[m >> 1].x;
        phase_barrier();

        // ---- Phase B: FWHT bits 4-7, in place ----
        {
            const int base = ((tid >> 4) << 8) | (tid & 15);
#pragma unroll
            for (int m = 0; m < 16; ++m) {
                const float val = trb[swzW(base | (m << 4))];
                if (m & 1) w[m >> 1].y = val; else w[m >> 1].x = val;
            }
            radix16(w);
#pragma unroll
            for (int m = 0; m < 16; ++m)
                trb[swzW(base | (m << 4))] = (m & 1) ? w[m >> 1].y : w[m >> 1].x;
        }
        phase_barrier();

        // ---- Phase C: FWHT bits 0-3, *u, FWHT bits 0-3 (b128, in place) ----
        {
            const int cb = tid << 4;
#pragma unroll
            for (int c = 0; c < 4; ++c) {
                const float4 f = *reinterpret_cast<const float4*>(&trb[swzW(cb | (c << 2))]);
                w[2 * c]     = (v2f){f.x, f.y};
                w[2 * c + 1] = (v2f){f.z, f.w};
            }
            radix16(w);
#pragma unroll
            for (int c = 0; c < 4; ++c) {
                const float4 uv = *reinterpret_cast<const float4*>(u + cb + (c << 2));
                w[2 * c]     = pkmul(w[2 * c],     (v2f){uv.x, uv.y});
                w[2 * c + 1] = pkmul(w[2 * c + 1], (v2f){uv.z, uv.w});
            }
            radix16(w);
#pragma unroll
            for (int c = 0; c < 4; ++c) {
                const float4 f = make_float4(w[2 * c].x, w[2 * c].y,
                                             w[2 * c + 1].x, w[2 * c + 1].y);
                *reinterpret_cast<float4*>(&trb[swzW(cb | (c << 2))]) = f;
            }
        }
        phase_barrier();

        // ---- Phase D: FWHT bits 4-7, in place ----
        {
            const int base = ((tid >> 4) << 8) | (tid & 15);
#pragma unroll
            for (int m = 0; m < 16; ++m) {
                const float val = trb[swzW(base | (m << 4))];
                if (m & 1) w[m >> 1].y = val; else w[m >> 1].x = val;
            }
            radix16(w);
#pragma unroll
            for (int m = 0; m < 16; ++m)
                trb[swzW(base | (m << 4))] = (m & 1) ? w[m >> 1].y : w[m >> 1].x;
        }
        phase_barrier();

        // ---- Phase E: FWHT bits 8-11, *s1, coalesced b32 stores ----
#pragma unroll
        for (int m = 0; m < 16; ++m) {
            const float val = trb[swzW(tid + (m << 8))];
            if (m & 1) w[m >> 1].y = val; else w[m >> 1].x = val;
        }
        radix16(w);
        float* __restrict__ orow = out + (size_t)row * D_DIM;
#pragma unroll
        for (int m = 0; m < 16; ++m) {
            const int i = tid + (m << 8);
            const float val = (m & 1) ? w[m >> 1].y : w[m >> 1].x;
            orow[i] = val * s1[i];
        }
        // trb reuse safety for next row's phase A (lgkm-only; stores fly on)
        phase_barrier();
    }
}

extern "C" void kernel_launch(void* const* d_in, const int* in_sizes, int n_in,
                              void* d_out, int out_size, void* d_ws, size_t ws_size,
                              hipStream_t stream) {
    const float* x     = (const float*)d_in[0];
    const float* s1    = (const float*)d_in[1];
    const float* s2    = (const float*)d_in[2];
    const float* g_mu  = (const float*)d_in[3];
    const float* g_rho = (const float*)d_in[4];
    const float* eps   = (const float*)d_in[5];
    // d_in[6] = H : realized implicitly by the FWHT butterflies.

    float* u   = (float*)d_ws;
    float* out = (float*)d_out;

    const int N = in_sizes[0] / D_DIM;

    compute_u_kernel<<<(D_DIM + 255) / 256, 256, 0, stream>>>(g_mu, g_rho, eps, u);
    whvi_kernel<<<NWG, 256, 0, stream>>>(x, s1, s2, u, out, N);
}

// Round 16
// 126.113 us; speedup vs baseline: 1.7090x; 1.7090x over previous
//
#include <hip/hip_runtime.h>
#include <math.h>

#define D_DIM 4096
#define NWG 1024  // 4 WGs/CU x 256 CUs, persistent grid-stride (16 rows/WG)

typedef float v2f __attribute__((ext_vector_type(2)));
typedef float v4f __attribute__((ext_vector_type(4)));

// ---- packed-f32 butterfly primitives (VOP3P) ----
__device__ __forceinline__ v2f bfly0(v2f a) {
    v2f d;
    asm("v_pk_add_f32 %0, %1, %2 op_sel:[0,1] op_sel_hi:[0,1] neg_hi:[0,1]"
        : "=v"(d) : "v"(a), "v"(a));
    return d;
}
__device__ __forceinline__ v2f pkadd(v2f a, v2f b) {
    v2f d; asm("v_pk_add_f32 %0, %1, %2" : "=v"(d) : "v"(a), "v"(b)); return d;
}
__device__ __forceinline__ v2f pksub(v2f a, v2f b) {
    v2f d; asm("v_pk_add_f32 %0, %1, %2 neg_lo:[0,1] neg_hi:[0,1]" : "=v"(d) : "v"(a), "v"(b)); return d;
}
__device__ __forceinline__ v2f pkmul(v2f a, v2f b) {
    v2f d; asm("v_pk_mul_f32 %0, %1, %2" : "=v"(d) : "v"(a), "v"(b)); return d;
}

// In-register FWHT over 4 bits: 16 values as 8 packed v2f (verified r2-r11).
__device__ __forceinline__ void radix16(v2f w[8]) {
#pragma unroll
    for (int p = 0; p < 8; ++p) w[p] = bfly0(w[p]);
#pragma unroll
    for (int s = 0; s < 3; ++s) {
        const int d = 1 << s;
#pragma unroll
        for (int p = 0; p < 8; ++p) {
            if (!(p & d)) {
                const v2f a = w[p];
                const v2f b = w[p + d];
                w[p]     = pkadd(a, b);
                w[p + d] = pksub(a, b);
            }
        }
    }
}

// async global->LDS, 16 B/lane; LDS dest = wave-uniform base + lane*16.
__device__ __forceinline__ void gload_lds16(const float* g, float* lp) {
    __builtin_amdgcn_global_load_lds(
        (const __attribute__((address_space(1))) void*)g,
        (__attribute__((address_space(3))) void*)lp, 16, 0, 0);
}

// ALL loop LDS ops as inline asm: invisible to LDS-DMA alias analysis ->
// the compiler cannot insert conservative vmcnt(0) drains before LDS reads
// (the suspected R11 residual). Correctness from my counted vmcnt + barriers.
// NOTE: asm vector operands must be native ext_vector types (v4f), not the
// HIP float4 class (inputs with class type fail: "indirect register inputs").
__device__ __forceinline__ v4f ds_read128(unsigned a) {
    v4f d; asm volatile("ds_read_b128 %0, %1" : "=v"(d) : "v"(a)); return d;
}
__device__ __forceinline__ void ds_write128(unsigned a, v4f v) {
    asm volatile("ds_write_b128 %0, %1" : : "v"(a), "v"(v));
}
__device__ __forceinline__ float ds_read32(unsigned a) {
    float d; asm volatile("ds_read_b32 %0, %1" : "=v"(d) : "v"(a)); return d;
}
__device__ __forceinline__ void ds_write32(unsigned a, float v) {
    asm volatile("ds_write_b32 %0, %1" : : "v"(a), "v"(v));
}
__device__ __forceinline__ void wait_lgkm0() {
    asm volatile("s_waitcnt lgkmcnt(0)" ::: "memory");
    __builtin_amdgcn_sched_barrier(0);
}
// Phase barrier: drain DS only; vmem (glds prefetch, stores) stays in flight.
__device__ __forceinline__ void phase_barrier() {
    asm volatile("s_waitcnt lgkmcnt(0)" ::: "memory");
    __builtin_amdgcn_s_barrier();
    __builtin_amdgcn_sched_barrier(0);
}

// Rank-complete swizzle (verified R11; same three patterns, phases renamed):
//   b4 ^= e8 ^ e5 ;  b3 ^= e7 ;  b2 ^= e9 ^ e6
// contig-b128 (A/E + stage): 8 lanes/quad = b128 floor; stride-16 (B/D) and
// stride-256 (C): 2-way (free). Bijective involution; bits 1:0 untouched.
__device__ __forceinline__ int swzW(int e) {
    const int x4 = ((e >> 8) ^ (e >> 5)) & 1;
    const int x3 = (e >> 7) & 1;
    const int x2 = ((e >> 9) ^ (e >> 6)) & 1;
    return e ^ (x4 << 4) ^ (x3 << 3) ^ (x2 << 2);
}

// Persistent cooperative kernel, R11 skeleton with reordered FWHT stages
// (bit-stages commute): A: bits 0-3 (contig b128), B: 4-7, C: 8-11 *u 8-11,
// D: 4-7, E: 0-3 (contig b128 -> float4 stores).
// Stage holds x PRE-SWIZZLED (per-lane swizzled glds SOURCE, linear LDS dest)
// so phase-A b128 reads are conflict-free. u computed in-prologue (fused).
// vmcnt algebra/row: [glds_next(4)] ... [stores(4)]; bottom vmcnt(4) retires
// exactly the glds BEFORE the barrier (all waves' DMA landed -> A may read).
__global__ __launch_bounds__(256, 4) void whvi_kernel(const float* __restrict__ x,
                                                      const float* __restrict__ s1,
                                                      const float* __restrict__ s2,
                                                      const float* __restrict__ g_mu,
                                                      const float* __restrict__ g_rho,
                                                      const float* __restrict__ eps,
                                                      float* __restrict__ out,
                                                      int nrows) {
    __shared__ float stg[D_DIM];  // x stage: linear glds dest, pre-swizzled content
    __shared__ float trb[D_DIM];  // transpose buffer, swzW layout
    const int tid = threadIdx.x;
    const int wv = tid >> 6;
    const int l6 = tid & 63;
    const unsigned sb = (unsigned)(uintptr_t)stg;
    const unsigned tb = (unsigned)(uintptr_t)trb;

    // ---- prologue: glds row0 first (oldest vmem) ----
    int row = blockIdx.x;
    if (row < nrows) {
        const float* xr = x + (size_t)row * D_DIM;
#pragma unroll
        for (int k = 0; k < 4; ++k) {
            const int B = (k << 10) | (wv << 8);
            gload_lds16(xr + swzW(B + (l6 << 2)), stg + B);
        }
    }

    // ---- persistent scales (contig per-thread -> float4) + fused u ----
    v4f S1v[4], S2v[4];
#pragma unroll
    for (int c = 0; c < 4; ++c) {
        S1v[c] = *reinterpret_cast<const v4f*>(s1 + (tid << 4) + (c << 2));
        S2v[c] = *reinterpret_cast<const v4f*>(s2 + (tid << 4) + (c << 2));
    }
    float Ur[16];
#pragma unroll
    for (int j = 0; j < 16; ++j) {
        const int i = tid + (j << 8);
        const float r = g_rho[i];
        const float sp = (r > 20.0f) ? r : log1pf(expf(r));
        Ur[j] = (g_mu[i] + sp * eps[i]) * 0.015625f;  // 1/64 norm folded
    }

    asm volatile("s_waitcnt vmcnt(0) lgkmcnt(0)" ::: "memory");
    __builtin_amdgcn_s_barrier();
    __builtin_amdgcn_sched_barrier(0);

    for (; row < nrows; row += NWG) {
        v2f w[8];

        // ---- Phase A: stage b128 reads (swz), *s2, FWHT bits 0-3, trb b128 writes ----
        {
            v4f F[4];
#pragma unroll
            for (int c = 0; c < 4; ++c)
                F[c] = ds_read128(sb + (unsigned)(swzW((tid << 4) | (c << 2)) << 2));
            wait_lgkm0();
#pragma unroll
            for (int c = 0; c < 4; ++c) {
                w[2 * c]     = pkmul((v2f){F[c].x, F[c].y}, (v2f){S2v[c].x, S2v[c].y});
                w[2 * c + 1] = pkmul((v2f){F[c].z, F[c].w}, (v2f){S2v[c].z, S2v[c].w});
            }
            radix16(w);
#pragma unroll
            for (int c = 0; c < 4; ++c) {
                const v4f o = {w[2 * c].x, w[2 * c].y, w[2 * c + 1].x, w[2 * c + 1].y};
                ds_write128(tb + (unsigned)(swzW((tid << 4) | (c << 2)) << 2), o);
            }
        }
        phase_barrier();  // also: all waves done reading stg

        // ---- prefetch next row into stage (pre-swizzled source) ----
        const int next = row + NWG;
        if (next < nrows) {
            const float* xn = x + (size_t)next * D_DIM;
#pragma unroll
            for (int k = 0; k < 4; ++k) {
                const int B = (k << 10) | (wv << 8);
                gload_lds16(xn + swzW(B + (l6 << 2)), stg + B);
            }
        }
        __builtin_amdgcn_sched_barrier(0);

        // ---- Phase B: FWHT bits 4-7 (stride-16, in place) ----
        {
            const int base = ((tid >> 4) << 8) | (tid & 15);
            float t[16];
#pragma unroll
            for (int m = 0; m < 16; ++m)
                t[m] = ds_read32(tb + (unsigned)(swzW(base | (m << 4)) << 2));
            wait_lgkm0();
#pragma unroll
            for (int m = 0; m < 16; ++m) {
                if (m & 1) w[m >> 1].y = t[m]; else w[m >> 1].x = t[m];
            }
            radix16(w);
#pragma unroll
            for (int m = 0; m < 16; ++m)
                ds_write32(tb + (unsigned)(swzW(base | (m << 4)) << 2),
                           (m & 1) ? w[m >> 1].y : w[m >> 1].x);
        }
        phase_barrier();

        // ---- Phase C: FWHT bits 8-11, *u, FWHT bits 8-11 (stride-256, in place) ----
        {
            float t[16];
#pragma unroll
            for (int j = 0; j < 16; ++j)
                t[j] = ds_read32(tb + (unsigned)(swzW(tid + (j << 8)) << 2));
            wait_lgkm0();
#pragma unroll
            for (int j = 0; j < 16; ++j) {
                if (j & 1) w[j >> 1].y = t[j]; else w[j >> 1].x = t[j];
            }
            radix16(w);
#pragma unroll
            for (int j = 0; j < 8; ++j)
                w[j] = pkmul(w[j], (v2f){Ur[2 * j], Ur[2 * j + 1]});
            radix16(w);
#pragma unroll
            for (int j = 0; j < 16; ++j)
                ds_write32(tb + (unsigned)(swzW(tid + (j << 8)) << 2),
                           (j & 1) ? w[j >> 1].y : w[j >> 1].x);
        }
        phase_barrier();

        // ---- Phase D: FWHT bits 4-7 (stride-16, in place) ----
        {
            const int base = ((tid >> 4) << 8) | (tid & 15);
            float t[16];
#pragma unroll
            for (int m = 0; m < 16; ++m)
                t[m] = ds_read32(tb + (unsigned)(swzW(base | (m << 4)) << 2));
            wait_lgkm0();
#pragma unroll
            for (int m = 0; m < 16; ++m) {
                if (m & 1) w[m >> 1].y = t[m]; else w[m >> 1].x = t[m];
            }
            radix16(w);
#pragma unroll
            for (int m = 0; m < 16; ++m)
                ds_write32(tb + (unsigned)(swzW(base | (m << 4)) << 2),
                           (m & 1) ? w[m >> 1].y : w[m >> 1].x);
        }
        phase_barrier();

        // ---- Phase E: trb b128 reads, FWHT bits 0-3, *s1, float4 stores ----
        {
            v4f G[4];
#pragma unroll
            for (int c = 0; c < 4; ++c)
                G[c] = ds_read128(tb + (unsigned)(swzW((tid << 4) | (c << 2)) << 2));
            wait_lgkm0();
#pragma unroll
            for (int c = 0; c < 4; ++c) {
                w[2 * c]     = (v2f){G[c].x, G[c].y};
                w[2 * c + 1] = (v2f){G[c].z, G[c].w};
            }
            radix16(w);
            float* orow = out + (size_t)row * D_DIM;
#pragma unroll
            for (int c = 0; c < 4; ++c) {
                const v2f o0 = pkmul(w[2 * c],     (v2f){S1v[c].x, S1v[c].y});
                const v2f o1 = pkmul(w[2 * c + 1], (v2f){S1v[c].z, S1v[c].w});
                const v4f ov = {o0.x, o0.y, o1.x, o1.y};
                *reinterpret_cast<v4f*>(orow + (tid << 4) + (c << 2)) = ov;
            }
        }

        // ---- bottom: retire exactly glds_next (stores stay in flight),
        //      THEN barrier -> every wave's DMA landed before any A-read ----
        __builtin_amdgcn_sched_barrier(0);
        asm volatile("s_waitcnt vmcnt(4)" ::: "memory");
        asm volatile("s_waitcnt lgkmcnt(0)" ::: "memory");
        __builtin_amdgcn_s_barrier();
        __builtin_amdgcn_sched_barrier(0);
    }
}

extern "C" void kernel_launch(void* const* d_in, const int* in_sizes, int n_in,
                              void* d_out, int out_size, void* d_ws, size_t ws_size,
                              hipStream_t stream) {
    const float* x     = (const float*)d_in[0];
    const float* s1    = (const float*)d_in[1];
    const float* s2    = (const float*)d_in[2];
    const float* g_mu  = (const float*)d_in[3];
    const float* g_rho = (const float*)d_in[4];
    const float* eps   = (const float*)d_in[5];
    // d_in[6] = H : realized implicitly by the FWHT butterflies.
    float* out = (float*)d_out;

    const int N = in_sizes[0] / D_DIM;

    whvi_kernel<<<NWG, 256, 0, stream>>>(x, s1, s2, g_mu, g_rho, eps, out, N);
}